// Round 9
// baseline (264.291 us; speedup 1.0000x reference)
//
#include <hip/hip_runtime.h>
#include <hip/hip_bf16.h>

// FourierKANLayer: N=4096, D_IN=512, D_OUT=512, G=32
// y = [cos/sin(k*LN(x)) features] @ W + bias  == GEMM M=4096,N=512,K=32768 (bf16 MFMA)
// R15: single-barrier phases. Intra-tile phases have NO cross-wave hazards
//      (reads hit tile-start-published buffers; writes go to next-tile
//      buffers), so the leading barrier + post-barrier lgkmcnt(0) of R13/R14
//      are removed: per phase {MFMA; issue reads(p+1); stage quarter; BAR}.
//      Early waves' LDS bursts drain while late waves finish MFMA -> the
//      LDS pipe and MFMA pipe finally overlap. 4 barriers/tile (was 8);
//      tile boundary keeps vmcnt(1)+lgkmcnt(0). Compiler's counted lgkmcnt
//      handles operand waits (m97: near-optimal).
//      + T1 XCD combo swizzle: 16 row-blocks sharing a B-panel (col,kz) on
//      one XCD -> panel L2-local (2 combos x 2MB = 4MB = L2).
// ws layout: [0,16MB)   csT float2[512][4096] = (cos xn, sin xn) seeds
//            [16MB,48MB) bf16 weights [2][512][16384] K-major (32 MiB)
//            [48MB,80MB) bf16 split-K partials [8][4096][512] (32 MiB)

#define N_ROWS 4096
#define D_IN   512
#define D_OUT  512
#define KT     16384   // per-trig K = D_IN*G
#define BM 256
#define BN 256
#define SPLITK 8
#define NT 64          // K-tiles per block: 2 trig x 32 dim-pairs (BK=64)

typedef short short8 __attribute__((ext_vector_type(8)));
typedef float float4v __attribute__((ext_vector_type(4)));

__device__ inline unsigned int pack2bf(float a, float b) {
    __hip_bfloat162 h = __float22bfloat162_rn(make_float2(a, b));
    union { __hip_bfloat162 h; unsigned int u; } cv;
    cv.h = h;
    return cv.u;
}

__device__ inline unsigned short bf16_1(float a) {
    union { float f; unsigned int u; } cv;
    cv.f = a;
    unsigned int r = (cv.u + 0x7fff + ((cv.u >> 16) & 1)) >> 16;  // RN-even
    return (unsigned short)r;
}

// ---- kernel 1: fused LN stats + sincos seeds + W cast (one launch) ----
__global__ __launch_bounds__(256) void pre_kernel(const float* __restrict__ x,
        const float* __restrict__ lnw, const float* __restrict__ lnb,
        const float* __restrict__ fc, float2* __restrict__ csT,
        unsigned short* __restrict__ Wb) {
    __shared__ __align__(16) float xs[16 * 516];
    __shared__ float2 murs[16];
    const int t = threadIdx.x;
    const int r0 = blockIdx.x * 16;
    {
        const int row = t >> 4, tq = t & 15;
        const float* xr = x + (size_t)(r0 + row) * D_IN;
        float s = 0.f, q = 0.f;
        #pragma unroll
        for (int k = 0; k < 8; ++k) {
            float4 v = *(const float4*)(xr + tq * 4 + k * 64);
            *(float4*)&xs[row * 516 + tq * 4 + k * 64] = v;
            s += v.x + v.y + v.z + v.w;
            q += v.x * v.x + v.y * v.y + v.z * v.z + v.w * v.w;
        }
        #pragma unroll
        for (int off = 8; off > 0; off >>= 1) {
            s += __shfl_xor(s, off, 16);
            q += __shfl_xor(q, off, 16);
        }
        if (tq == 0) {
            float mu = s * (1.f / D_IN);
            float var = q * (1.f / D_IN) - mu * mu;
            murs[row] = make_float2(mu, rsqrtf(var + 1e-5f));
        }
    }
    __syncthreads();
    {
        const int brow = t & 15, dimg = t >> 4;
        const float2 mr = murs[brow];
        #pragma unroll 4
        for (int j = 0; j < 32; ++j) {
            const int dim = j * 16 + dimg;
            float xv = xs[brow * 516 + dim];
            float xn = (xv - mr.x) * mr.y * lnw[dim] + lnb[dim];
            float s1, c1;
            __sincosf(xn, &s1, &c1);
            csT[(size_t)dim * N_ROWS + r0 + brow] = make_float2(c1, s1);
        }
    }
    {   // W cast: 16.78M floats = 256 blk x 256 thr x 8 x 32
        size_t e = ((size_t)blockIdx.x * 256 + t) * 8;
        for (int it2 = 0; it2 < 32; ++it2, e += (size_t)256 * 256 * 8) {
            const float4* in = (const float4*)(fc + e);
            float4 a = in[0], c = in[1];
            uint4 o;
            o.x = pack2bf(a.x, a.y);
            o.y = pack2bf(a.z, a.w);
            o.z = pack2bf(c.x, c.y);
            o.w = pack2bf(c.z, c.w);
            *(uint4*)(Wb + e) = o;
        }
    }
}

// ---- feature staging (full tile, prologue only): Chebyshev -> swizzled A ----
// A layout: [row][64 shorts], 16B chunk kc stored at chunk index kc^(row&7).
__device__ inline void stage_feats(unsigned short* Abuf, float2 cs, int ttype,
                                   int frow, int ihalf) {
    const float c1 = cs.x, s1 = cs.y;
    const float c2 = c1 + c1;
    float prev = ttype ? 0.f : 1.f;
    float cur  = ttype ? s1 : c1;
    const int rbase = frow * 64;
    const int sw = frow & 7;
    unsigned int us[4];
    #pragma unroll
    for (int d = 0; d < 16; ++d) {
        float f0 = cur;
        float f1 = __builtin_fmaf(c2, cur, -prev);
        float f2 = __builtin_fmaf(c2, f1, -cur);
        prev = f1;
        cur = f2;
        us[d & 3] = pack2bf(f0, f1);
        if ((d & 3) == 3) {
            const int kc = ihalf * 4 + (d >> 2);
            *(uint4*)&Abuf[rbase + ((kc ^ sw) << 3)] =
                make_uint4(us[0], us[1], us[2], us[3]);
        }
    }
}

__device__ inline void gl_lds16(const unsigned short* gsrc, unsigned short* ldst) {
    __builtin_amdgcn_global_load_lds(
        (const __attribute__((address_space(1))) unsigned int*)gsrc,
        (__attribute__((address_space(3))) unsigned int*)ldst, 16, 0, 0);
}

#define PACING_BAR() do { asm volatile("" ::: "memory"); \
    __builtin_amdgcn_s_barrier(); asm volatile("" ::: "memory"); } while (0)

// ---- one K-tile: 4 MFMA bursts, 3 pacing barriers, 1 boundary fence ----
template<bool PF>
__device__ __forceinline__ void gemm_tile(int tt,
        const unsigned short* Ap, const unsigned short* Bp,
        unsigned short* Aw, unsigned short* Bw,
        const unsigned short* Bg0, const float2* csBase, float2& csA,
        int wv, int wrow, int lm, int lq, int swA, int bBase,
        int arow, int adim, float4v (&acc)[8][4]) {
    // Chebyshev chain for A(tt+1): 8 harmonics advanced per quarter
    const int ttype1 = ((tt + 1) >> 5) & 1;
    const float c2 = csA.x + csA.x;
    float prev = ttype1 ? 0.f : 1.f;
    float cur  = ttype1 ? csA.y : csA.x;
    float2 csN = csA;

    // A-read helper (mh selects m-frag half, h selects k-half)
    #define A_RD(mh, j, h) (*(const short8*)\
        &Ap[(wrow * 128 + (4 * (mh) + (j)) * 16 + lm) * 64 \
            + ((((h) * 4 + lq) ^ swA) << 3)])
    #define B_RD(n, h) (*(const short8*)&Bp[bBase + (n) * 1024 + (h) * 256])
    #define MFMA16(AF, BF, mh) do { __builtin_amdgcn_s_setprio(1); \
        _Pragma("unroll") for (int j = 0; j < 4; ++j) \
            _Pragma("unroll") for (int n = 0; n < 4; ++n) \
                acc[4 * (mh) + j][n] = __builtin_amdgcn_mfma_f32_16x16x32_bf16( \
                    AF[j], BF[n], acc[4 * (mh) + j][n], 0, 0, 0); \
        __builtin_amdgcn_s_setprio(0); } while (0)
    #define STAGE_Q(q) do { unsigned int us[4]; \
        _Pragma("unroll") for (int d = 0; d < 4; ++d) { \
            float f0 = cur; \
            float f1 = __builtin_fmaf(c2, cur, -prev); \
            us[d] = pack2bf(f0, f1); \
            float f2 = __builtin_fmaf(c2, f1, -cur); \
            prev = f1; cur = f2; } \
        const int kc = adim * 4 + (q); \
        *(uint4*)&Aw[arow * 64 + ((kc ^ (arow & 7)) << 3)] = \
            make_uint4(us[0], us[1], us[2], us[3]); } while (0)

    // ---- phase 0 (mh0,h0): reads post-tile-barrier, MFMA
    short8 af0[4], bfA[4];
    #pragma unroll
    for (int j = 0; j < 4; ++j) af0[j] = A_RD(0, j, 0);
    #pragma unroll
    for (int n = 0; n < 4; ++n) bfA[n] = B_RD(n, 0);
    MFMA16(af0, bfA, 0);
    // post-MFMA p0: DMA B(tt+1), seed(tt+2), reads(p1), stage q0
    if (PF) {
        const int n1 = tt + 1;
        const unsigned short* gb =
            Bg0 + (size_t)(n1 >> 5) * D_OUT * KT + (n1 & 31) * 64;
        unsigned short* ldst = Bw + (wv * 4) * 512;
        #pragma unroll
        for (int j2 = 0; j2 < 4; ++j2)
            gl_lds16(gb + (size_t)(j2 * 8) * KT, ldst + j2 * 512);
        __builtin_amdgcn_sched_barrier(0);   // pin: gl_lds before seed load
        csN = csBase[(size_t)(((tt + 2) & 31) * 2) * N_ROWS];
    }
    short8 af1[4];
    #pragma unroll
    for (int j = 0; j < 4; ++j) af1[j] = A_RD(1, j, 0);
    if (PF) STAGE_Q(0);
    PACING_BAR();
    // ---- phase 1 (mh1,h0)
    MFMA16(af1, bfA, 1);
    short8 af2[4], bfB[4];
    #pragma unroll
    for (int j = 0; j < 4; ++j) af2[j] = A_RD(0, j, 1);
    #pragma unroll
    for (int n = 0; n < 4; ++n) bfB[n] = B_RD(n, 1);
    if (PF) STAGE_Q(1);
    PACING_BAR();
    // ---- phase 2 (mh0,h1)
    MFMA16(af2, bfB, 0);
    short8 af3[4];
    #pragma unroll
    for (int j = 0; j < 4; ++j) af3[j] = A_RD(1, j, 1);
    if (PF) STAGE_Q(2);
    PACING_BAR();
    // ---- phase 3 (mh1,h1)
    MFMA16(af3, bfB, 1);
    if (PF) {
        STAGE_Q(3);
        // boundary: 4 gl_lds landed + own reads/writes drained; seed in flight
        asm volatile("s_waitcnt vmcnt(1) lgkmcnt(0)" ::: "memory");
        __builtin_amdgcn_s_barrier();
        asm volatile("" ::: "memory");
        csA = csN;
    }
    #undef A_RD
    #undef B_RD
    #undef MFMA16
    #undef STAGE_Q
}

// ---- kernel 2: fused feature-gen + bf16 MFMA GEMM, 256^2 single-bar phases ----
// grid 16x2x8 = 256 blocks x 512 thr = 1 block/CU. XCD combo swizzle: the 16
// row-blocks sharing a B-panel (col,kz) map to one XCD (combo c -> XCD c%8).
__global__ __launch_bounds__(512, 2) void fkan_gemm(const float2* __restrict__ csT,
        const unsigned short* __restrict__ Wb, unsigned short* __restrict__ pb) {
    __shared__ unsigned short As[2][BM * 64];   // 2 x 32 KB, XOR-swizzled
    __shared__ unsigned short Bs[2][BN * 64];   // 2 x 32 KB (gl_lds dest)
    const int t = threadIdx.x;
    // T1 combo swizzle (bijective on [0,256)): lb -> (x row-tile, combo=(y,z))
    const int lb = blockIdx.x + 16 * (blockIdx.y + 2 * blockIdx.z);
    const int combo = (lb & 7) + 8 * (lb >> 7);
    const int xrt = (lb >> 3) & 15;
    const int row0 = xrt * BM;
    const int col0 = (combo & 1) * BN;
    const int kz = combo >> 1;
    const int k0 = kz * 2048;            // within-trig k offset (64 dims x 32)
    const int i0 = kz * 64;              // starting input dim for this chunk
    const int l = t & 63, wv = t >> 6;
    const int wrow = wv >> 2, wcol = wv & 3;   // wave grid 2M x 4N
    const int lm = l & 15, lq = l >> 4;
    const int swA = lm & 7;
    const int arow = t & 255, adim = t >> 8;   // A-staging unit (row, dim-half)
    // gl_lds B staging: wave wv covers cols [col0+wv*32,+32), 4 x (8col x 128B)
    const int c8 = l & 7, s8 = l >> 3;
    const unsigned short* Bg0 =
        Wb + (size_t)(col0 + wv * 32 + c8) * KT + k0 + s8 * 8;
    // B-frag read base (shorts): colgrp*512 + kseg*64 + (col&7)*8
    const int bBase = (wcol * 8 + (lm >> 3)) * 512 + lq * 64 + (lm & 7) * 8;
    const float2* csBase = csT + (size_t)(i0 + adim) * N_ROWS + row0 + arow;

    float4v acc[8][4];
    #pragma unroll
    for (int i = 0; i < 8; ++i)
        #pragma unroll
        for (int j = 0; j < 4; ++j)
            acc[i][j] = (float4v){0.f, 0.f, 0.f, 0.f};

    // ---- prologue: seed(0) -> stage A(0); gl_lds B(0); seed(1) in flight
    float2 cs0 = csBase[0];
    #pragma unroll
    for (int j = 0; j < 4; ++j)
        gl_lds16(Bg0 + (size_t)(j * 8) * KT, &Bs[0][(wv * 4 + j) * 512]);
    __builtin_amdgcn_sched_barrier(0);           // pin: gl_lds before seed load
    float2 csA = csBase[2 * N_ROWS];             // seed(1)
    stage_feats(&As[0][0], cs0, 0, arow, adim);
    asm volatile("s_waitcnt vmcnt(1) lgkmcnt(0)" ::: "memory");
    __builtin_amdgcn_s_barrier();
    asm volatile("" ::: "memory");

    #pragma unroll 1
    for (int tt = 0; tt < NT - 1; ++tt)
        gemm_tile<true>(tt, &As[tt & 1][0], &Bs[tt & 1][0],
                        &As[(tt + 1) & 1][0], &Bs[(tt + 1) & 1][0],
                        Bg0, csBase, csA, wv, wrow, lm, lq, swA, bBase,
                        arow, adim, acc);
    gemm_tile<false>(NT - 1, &As[1][0], &Bs[1][0], &As[0][0], &Bs[0][0],
                     Bg0, csBase, csA, wv, wrow, lm, lq, swA, bBase,
                     arow, adim, acc);

    // epilogue: C/D layout col=lane&15, row=quad*4+reg (m89-verified)
    unsigned short* pc = pb + (size_t)kz * N_ROWS * D_OUT;
    #pragma unroll
    for (int m = 0; m < 8; ++m)
        #pragma unroll
        for (int n = 0; n < 4; ++n)
            #pragma unroll
            for (int r = 0; r < 4; ++r) {
                const int row = row0 + wrow * 128 + m * 16 + lq * 4 + r;
                const int col = col0 + wcol * 64 + n * 16 + lm;
                pc[(size_t)row * D_OUT + col] = bf16_1(acc[m][n][r]);
            }
}

// ---- kernel 3: out = bias + sum of 8 bf16 partials (8 shorts/lane) ----
__global__ __launch_bounds__(256) void reduce_kernel(const unsigned short* __restrict__ pb,
        const float* __restrict__ bias, float* __restrict__ out) {
    const size_t e = ((size_t)blockIdx.x * 256 + threadIdx.x) * 8;
    const int col = (int)(e & (D_OUT - 1));
    float4 s0 = *(const float4*)(bias + col);
    float4 s1 = *(const float4*)(bias + col + 4);
    #pragma unroll
    for (int c = 0; c < SPLITK; ++c) {
        uint4 u = *(const uint4*)(pb + (size_t)c * N_ROWS * D_OUT + e);
        union { unsigned int u; float f; } lo, hi;
        lo.u = u.x << 16;            hi.u = u.x & 0xffff0000u;
        s0.x += lo.f;                s0.y += hi.f;
        lo.u = u.y << 16;            hi.u = u.y & 0xffff0000u;
        s0.z += lo.f;                s0.w += hi.f;
        lo.u = u.z << 16;            hi.u = u.z & 0xffff0000u;
        s1.x += lo.f;                s1.y += hi.f;
        lo.u = u.w << 16;            hi.u = u.w & 0xffff0000u;
        s1.z += lo.f;                s1.w += hi.f;
    }
    *(float4*)(out + e) = s0;
    *(float4*)(out + e + 4) = s1;
}

extern "C" void kernel_launch(void* const* d_in, const int* in_sizes, int n_in,
                              void* d_out, int out_size, void* d_ws, size_t ws_size,
                              hipStream_t stream) {
    const float* x    = (const float*)d_in[0];
    const float* ln_w = (const float*)d_in[1];
    const float* ln_b = (const float*)d_in[2];
    const float* fc   = (const float*)d_in[3];
    const float* bias = (const float*)d_in[4];
    float* out = (float*)d_out;

    float2* csT = (float2*)d_ws;                                        // 16 MB
    unsigned short* Wb = (unsigned short*)((char*)d_ws + (16u << 20));  // 32 MB
    unsigned short* pbp = (unsigned short*)((char*)d_ws + (48u << 20)); // 32 MB

    pre_kernel<<<256, 256, 0, stream>>>(x, ln_w, ln_b, fc, csT, Wb);
    fkan_gemm<<<dim3(N_ROWS / BM, D_OUT / BN, SPLITK), 512, 0, stream>>>(csT, Wb, pbp);
    reduce_kernel<<<1024, 256, 0, stream>>>(pbp, bias, out);            // 2.10M outs
}

// Round 10
// 249.918 us; speedup vs baseline: 1.0575x; 1.0575x over previous
//
#include <hip/hip_runtime.h>
#include <hip/hip_bf16.h>

// FourierKANLayer: N=4096, D_IN=512, D_OUT=512, G=32
// y = [cos/sin(k*LN(x)) features] @ W + bias  == GEMM M=4096,N=512,K=32768 (bf16 MFMA)
// R16: ZERO intra-tile barriers. One fence+barrier per K-tile (boundary only);
//      the whole tile {24 ds_reads, 64 MFMA, 4 stage-writes, 4 gl_lds, seed}
//      is a single compiler-scheduled region (counted lgkmcnt interleave,
//      m97-proven). Wave groups de-phase via asymmetric setprio: waves 0-3
//      run prio1 from boundary until end of h0 MFMAs -> head start -> G1's
//      reads drain under G0's MFMAs and vice versa. Legality: intra-tile,
//      waves only READ published [tt&1] bufs and WRITE [(tt+1)&1] bufs.
//      Boundary: vmcnt(1) lgkmcnt(0) + s_barrier + compiler fence (rule #18).
//      XCD combo swizzle kept (R15: FETCH 147.8->49.7 MB).
// ws layout: [0,16MB)   csT float2[512][4096] = (cos xn, sin xn) seeds
//            [16MB,48MB) bf16 weights [2][512][16384] K-major (32 MiB)
//            [48MB,80MB) bf16 split-K partials [8][4096][512] (32 MiB)

#define N_ROWS 4096
#define D_IN   512
#define D_OUT  512
#define KT     16384   // per-trig K = D_IN*G
#define BM 256
#define BN 256
#define SPLITK 8
#define NT 64          // K-tiles per block: 2 trig x 32 dim-pairs (BK=64)

typedef short short8 __attribute__((ext_vector_type(8)));
typedef float float4v __attribute__((ext_vector_type(4)));

__device__ inline unsigned int pack2bf(float a, float b) {
    __hip_bfloat162 h = __float22bfloat162_rn(make_float2(a, b));
    union { __hip_bfloat162 h; unsigned int u; } cv;
    cv.h = h;
    return cv.u;
}

__device__ inline unsigned short bf16_1(float a) {
    union { float f; unsigned int u; } cv;
    cv.f = a;
    unsigned int r = (cv.u + 0x7fff + ((cv.u >> 16) & 1)) >> 16;  // RN-even
    return (unsigned short)r;
}

// ---- kernel 1: fused LN stats + sincos seeds + W cast (one launch) ----
__global__ __launch_bounds__(256) void pre_kernel(const float* __restrict__ x,
        const float* __restrict__ lnw, const float* __restrict__ lnb,
        const float* __restrict__ fc, float2* __restrict__ csT,
        unsigned short* __restrict__ Wb) {
    __shared__ __align__(16) float xs[16 * 516];
    __shared__ float2 murs[16];
    const int t = threadIdx.x;
    const int r0 = blockIdx.x * 16;
    {
        const int row = t >> 4, tq = t & 15;
        const float* xr = x + (size_t)(r0 + row) * D_IN;
        float s = 0.f, q = 0.f;
        #pragma unroll
        for (int k = 0; k < 8; ++k) {
            float4 v = *(const float4*)(xr + tq * 4 + k * 64);
            *(float4*)&xs[row * 516 + tq * 4 + k * 64] = v;
            s += v.x + v.y + v.z + v.w;
            q += v.x * v.x + v.y * v.y + v.z * v.z + v.w * v.w;
        }
        #pragma unroll
        for (int off = 8; off > 0; off >>= 1) {
            s += __shfl_xor(s, off, 16);
            q += __shfl_xor(q, off, 16);
        }
        if (tq == 0) {
            float mu = s * (1.f / D_IN);
            float var = q * (1.f / D_IN) - mu * mu;
            murs[row] = make_float2(mu, rsqrtf(var + 1e-5f));
        }
    }
    __syncthreads();
    {
        const int brow = t & 15, dimg = t >> 4;
        const float2 mr = murs[brow];
        #pragma unroll 4
        for (int j = 0; j < 32; ++j) {
            const int dim = j * 16 + dimg;
            float xv = xs[brow * 516 + dim];
            float xn = (xv - mr.x) * mr.y * lnw[dim] + lnb[dim];
            float s1, c1;
            __sincosf(xn, &s1, &c1);
            csT[(size_t)dim * N_ROWS + r0 + brow] = make_float2(c1, s1);
        }
    }
    {   // W cast: 16.78M floats = 256 blk x 256 thr x 8 x 32
        size_t e = ((size_t)blockIdx.x * 256 + t) * 8;
        for (int it2 = 0; it2 < 32; ++it2, e += (size_t)256 * 256 * 8) {
            const float4* in = (const float4*)(fc + e);
            float4 a = in[0], c = in[1];
            uint4 o;
            o.x = pack2bf(a.x, a.y);
            o.y = pack2bf(a.z, a.w);
            o.z = pack2bf(c.x, c.y);
            o.w = pack2bf(c.z, c.w);
            *(uint4*)(Wb + e) = o;
        }
    }
}

// ---- feature staging (full tile, prologue only): Chebyshev -> swizzled A ----
// A layout: [row][64 shorts], 16B chunk kc stored at chunk index kc^(row&7).
__device__ inline void stage_feats(unsigned short* Abuf, float2 cs, int ttype,
                                   int frow, int ihalf) {
    const float c1 = cs.x, s1 = cs.y;
    const float c2 = c1 + c1;
    float prev = ttype ? 0.f : 1.f;
    float cur  = ttype ? s1 : c1;
    const int rbase = frow * 64;
    const int sw = frow & 7;
    unsigned int us[4];
    #pragma unroll
    for (int d = 0; d < 16; ++d) {
        float f0 = cur;
        float f1 = __builtin_fmaf(c2, cur, -prev);
        float f2 = __builtin_fmaf(c2, f1, -cur);
        prev = f1;
        cur = f2;
        us[d & 3] = pack2bf(f0, f1);
        if ((d & 3) == 3) {
            const int kc = ihalf * 4 + (d >> 2);
            *(uint4*)&Abuf[rbase + ((kc ^ sw) << 3)] =
                make_uint4(us[0], us[1], us[2], us[3]);
        }
    }
}

__device__ inline void gl_lds16(const unsigned short* gsrc, unsigned short* ldst) {
    __builtin_amdgcn_global_load_lds(
        (const __attribute__((address_space(1))) unsigned int*)gsrc,
        (__attribute__((address_space(3))) unsigned int*)ldst, 16, 0, 0);
}

// ---- one K-tile: single scheduling region, boundary fence only ----
template<bool PF>
__device__ __forceinline__ void gemm_tile(int tt,
        const unsigned short* Ap, const unsigned short* Bp,
        unsigned short* Aw, unsigned short* Bw,
        const unsigned short* Bg0, const float2* csBase, float2& csA,
        int wv, int wrow, int lm, int lq, int swA, int bBase,
        int arow, int adim, bool g0, float4v (&acc)[8][4]) {
    // Chebyshev chain for A(tt+1): 8 harmonics advanced per quarter
    const int ttype1 = ((tt + 1) >> 5) & 1;
    const float c2 = csA.x + csA.x;
    float prev = ttype1 ? 0.f : 1.f;
    float cur  = ttype1 ? csA.y : csA.x;
    float2 csN = csA;

    #define A_RD(mh, j, h) (*(const short8*)\
        &Ap[(wrow * 128 + (4 * (mh) + (j)) * 16 + lm) * 64 \
            + ((((h) * 4 + lq) ^ swA) << 3)])
    #define B_RD(n, h) (*(const short8*)&Bp[bBase + (n) * 1024 + (h) * 256])
    #define MFMA16(AF, BF, mh) do { \
        _Pragma("unroll") for (int j = 0; j < 4; ++j) \
            _Pragma("unroll") for (int n = 0; n < 4; ++n) \
                acc[4 * (mh) + j][n] = __builtin_amdgcn_mfma_f32_16x16x32_bf16( \
                    AF[j], BF[n], acc[4 * (mh) + j][n], 0, 0, 0); } while (0)
    #define STAGE_Q(q) do { unsigned int us[4]; \
        _Pragma("unroll") for (int d = 0; d < 4; ++d) { \
            float f0 = cur; \
            float f1 = __builtin_fmaf(c2, cur, -prev); \
            us[d] = pack2bf(f0, f1); \
            float f2 = __builtin_fmaf(c2, f1, -cur); \
            prev = f1; cur = f2; } \
        const int kc = adim * 4 + (q); \
        *(uint4*)&Aw[arow * 64 + ((kc ^ (arow & 7)) << 3)] = \
            make_uint4(us[0], us[1], us[2], us[3]); } while (0)

    // de-phasing: G0 (waves 0-3) gets priority through its h0 MFMAs
    if (g0) __builtin_amdgcn_s_setprio(1);

    // h0 operands
    short8 bfA[4], af0[4], af1[4];
    #pragma unroll
    for (int n = 0; n < 4; ++n) bfA[n] = B_RD(n, 0);
    #pragma unroll
    for (int j = 0; j < 4; ++j) af0[j] = A_RD(0, j, 0);
    if (PF) {   // B(tt+1) DMA + seed(tt+2): issued early, drain at boundary
        const int n1 = tt + 1;
        const unsigned short* gb =
            Bg0 + (size_t)(n1 >> 5) * D_OUT * KT + (n1 & 31) * 64;
        unsigned short* ldst = Bw + (wv * 4) * 512;
        #pragma unroll
        for (int j2 = 0; j2 < 4; ++j2)
            gl_lds16(gb + (size_t)(j2 * 8) * KT, ldst + j2 * 512);
        __builtin_amdgcn_sched_barrier(0);   // pin: gl_lds before seed load
        csN = csBase[(size_t)(((tt + 2) & 31) * 2) * N_ROWS];
    }
    MFMA16(af0, bfA, 0);
    #pragma unroll
    for (int j = 0; j < 4; ++j) af1[j] = A_RD(1, j, 0);
    if (PF) STAGE_Q(0);
    MFMA16(af1, bfA, 1);
    if (g0) __builtin_amdgcn_s_setprio(0);   // head start spent
    // h1 operands
    short8 bfB[4], af2[4], af3[4];
    #pragma unroll
    for (int n = 0; n < 4; ++n) bfB[n] = B_RD(n, 1);
    #pragma unroll
    for (int j = 0; j < 4; ++j) af2[j] = A_RD(0, j, 1);
    if (PF) STAGE_Q(1);
    MFMA16(af2, bfB, 0);
    #pragma unroll
    for (int j = 0; j < 4; ++j) af3[j] = A_RD(1, j, 1);
    if (PF) STAGE_Q(2);
    MFMA16(af3, bfB, 1);
    if (PF) {
        STAGE_Q(3);
        // boundary: 4 gl_lds + all own LDS reads/writes drained; new seed
        // stays in flight (never vmcnt 0 mid-loop).
        asm volatile("s_waitcnt vmcnt(1) lgkmcnt(0)" ::: "memory");
        __builtin_amdgcn_s_barrier();
        asm volatile("" ::: "memory");
        csA = csN;
    }
    #undef A_RD
    #undef B_RD
    #undef MFMA16
    #undef STAGE_Q
}

// ---- kernel 2: fused feature-gen + bf16 MFMA GEMM, 256^2, 1 barrier/tile ----
// grid 16x2x8 = 256 blocks x 512 thr = 1 block/CU. XCD combo swizzle: the 16
// row-blocks sharing a B-panel (col,kz) map to one XCD (combo c -> XCD c%8).
__global__ __launch_bounds__(512, 2) void fkan_gemm(const float2* __restrict__ csT,
        const unsigned short* __restrict__ Wb, unsigned short* __restrict__ pb) {
    __shared__ unsigned short As[2][BM * 64];   // 2 x 32 KB, XOR-swizzled
    __shared__ unsigned short Bs[2][BN * 64];   // 2 x 32 KB (gl_lds dest)
    const int t = threadIdx.x;
    // T1 combo swizzle (bijective on [0,256)): lb -> (x row-tile, combo=(y,z))
    const int lb = blockIdx.x + 16 * (blockIdx.y + 2 * blockIdx.z);
    const int combo = (lb & 7) + 8 * (lb >> 7);
    const int xrt = (lb >> 3) & 15;
    const int row0 = xrt * BM;
    const int col0 = (combo & 1) * BN;
    const int kz = combo >> 1;
    const int k0 = kz * 2048;            // within-trig k offset (64 dims x 32)
    const int i0 = kz * 64;              // starting input dim for this chunk
    const int l = t & 63, wv = t >> 6;
    const int wrow = wv >> 2, wcol = wv & 3;   // wave grid 2M x 4N
    const int lm = l & 15, lq = l >> 4;
    const int swA = lm & 7;
    const int arow = t & 255, adim = t >> 8;   // A-staging unit (row, dim-half)
    const bool g0 = (wv < 4);                  // priority group
    // gl_lds B staging: wave wv covers cols [col0+wv*32,+32), 4 x (8col x 128B)
    const int c8 = l & 7, s8 = l >> 3;
    const unsigned short* Bg0 =
        Wb + (size_t)(col0 + wv * 32 + c8) * KT + k0 + s8 * 8;
    // B-frag read base (shorts): colgrp*512 + kseg*64 + (col&7)*8
    const int bBase = (wcol * 8 + (lm >> 3)) * 512 + lq * 64 + (lm & 7) * 8;
    const float2* csBase = csT + (size_t)(i0 + adim) * N_ROWS + row0 + arow;

    float4v acc[8][4];
    #pragma unroll
    for (int i = 0; i < 8; ++i)
        #pragma unroll
        for (int j = 0; j < 4; ++j)
            acc[i][j] = (float4v){0.f, 0.f, 0.f, 0.f};

    // ---- prologue: seed(0) -> stage A(0); gl_lds B(0); seed(1) in flight
    float2 cs0 = csBase[0];
    #pragma unroll
    for (int j = 0; j < 4; ++j)
        gl_lds16(Bg0 + (size_t)(j * 8) * KT, &Bs[0][(wv * 4 + j) * 512]);
    __builtin_amdgcn_sched_barrier(0);           // pin: gl_lds before seed load
    float2 csA = csBase[2 * N_ROWS];             // seed(1)
    stage_feats(&As[0][0], cs0, 0, arow, adim);
    asm volatile("s_waitcnt vmcnt(1) lgkmcnt(0)" ::: "memory");
    __builtin_amdgcn_s_barrier();
    asm volatile("" ::: "memory");

    #pragma unroll 1
    for (int tt = 0; tt < NT - 1; ++tt)
        gemm_tile<true>(tt, &As[tt & 1][0], &Bs[tt & 1][0],
                        &As[(tt + 1) & 1][0], &Bs[(tt + 1) & 1][0],
                        Bg0, csBase, csA, wv, wrow, lm, lq, swA, bBase,
                        arow, adim, g0, acc);
    gemm_tile<false>(NT - 1, &As[1][0], &Bs[1][0], &As[0][0], &Bs[0][0],
                     Bg0, csBase, csA, wv, wrow, lm, lq, swA, bBase,
                     arow, adim, g0, acc);

    // epilogue: C/D layout col=lane&15, row=quad*4+reg (m89-verified)
    unsigned short* pc = pb + (size_t)kz * N_ROWS * D_OUT;
    #pragma unroll
    for (int m = 0; m < 8; ++m)
        #pragma unroll
        for (int n = 0; n < 4; ++n)
            #pragma unroll
            for (int r = 0; r < 4; ++r) {
                const int row = row0 + wrow * 128 + m * 16 + lq * 4 + r;
                const int col = col0 + wcol * 64 + n * 16 + lm;
                pc[(size_t)row * D_OUT + col] = bf16_1(acc[m][n][r]);
            }
}

// ---- kernel 3: out = bias + sum of 8 bf16 partials (8 shorts/lane) ----
__global__ __launch_bounds__(256) void reduce_kernel(const unsigned short* __restrict__ pb,
        const float* __restrict__ bias, float* __restrict__ out) {
    const size_t e = ((size_t)blockIdx.x * 256 + threadIdx.x) * 8;
    const int col = (int)(e & (D_OUT - 1));
    float4 s0 = *(const float4*)(bias + col);
    float4 s1 = *(const float4*)(bias + col + 4);
    #pragma unroll
    for (int c = 0; c < SPLITK; ++c) {
        uint4 u = *(const uint4*)(pb + (size_t)c * N_ROWS * D_OUT + e);
        union { unsigned int u; float f; } lo, hi;
        lo.u = u.x << 16;            hi.u = u.x & 0xffff0000u;
        s0.x += lo.f;                s0.y += hi.f;
        lo.u = u.y << 16;            hi.u = u.y & 0xffff0000u;
        s0.z += lo.f;                s0.w += hi.f;
        lo.u = u.z << 16;            hi.u = u.z & 0xffff0000u;
        s1.x += lo.f;                s1.y += hi.f;
        lo.u = u.w << 16;            hi.u = u.w & 0xffff0000u;
        s1.z += lo.f;                s1.w += hi.f;
    }
    *(float4*)(out + e) = s0;
    *(float4*)(out + e + 4) = s1;
}

extern "C" void kernel_launch(void* const* d_in, const int* in_sizes, int n_in,
                              void* d_out, int out_size, void* d_ws, size_t ws_size,
                              hipStream_t stream) {
    const float* x    = (const float*)d_in[0];
    const float* ln_w = (const float*)d_in[1];
    const float* ln_b = (const float*)d_in[2];
    const float* fc   = (const float*)d_in[3];
    const float* bias = (const float*)d_in[4];
    float* out = (float*)d_out;

    float2* csT = (float2*)d_ws;                                        // 16 MB
    unsigned short* Wb = (unsigned short*)((char*)d_ws + (16u << 20));  // 32 MB
    unsigned short* pbp = (unsigned short*)((char*)d_ws + (48u << 20)); // 32 MB

    pre_kernel<<<256, 256, 0, stream>>>(x, ln_w, ln_b, fc, csT, Wb);
    fkan_gemm<<<dim3(N_ROWS / BM, D_OUT / BN, SPLITK), 512, 0, stream>>>(csT, Wb, pbp);
    reduce_kernel<<<1024, 256, 0, stream>>>(pbp, bias, out);            // 2.10M outs
}